// Round 11
// baseline (183.833 us; speedup 1.0000x reference)
//
#include <hip/hip_runtime.h>
#include <cstdint>

#define B_SZ 8192
#define D_SZ 512
#define K_SZ 2048
#define EPSV 1e-8f
// 1/TEMP
#define INV_T 2.0f

typedef float floatx16 __attribute__((ext_vector_type(16)));
typedef int intx8 __attribute__((ext_vector_type(8)));

// async global->LDS, 16B per lane. LDS dest must be wave-uniform base + lane*16.
__device__ __forceinline__ void async_cp16(const void* g, void* l) {
    typedef __attribute__((address_space(1))) unsigned int gds_t;
    typedef __attribute__((address_space(3))) unsigned int lds_t;
    __builtin_amdgcn_global_load_lds((gds_t*)(unsigned long long)g, (lds_t*)l, 16, 0, 0);
}

// pack 8 fp32 -> 8 fp8 e4m3 (OCP, RNE, saturating) as int2
__device__ __forceinline__ int2 pack_fp8x8(float4 a0, float4 a1) {
    int w0 = __builtin_amdgcn_cvt_pk_fp8_f32(a0.x, a0.y, 0, false);
    w0 = __builtin_amdgcn_cvt_pk_fp8_f32(a0.z, a0.w, w0, true);
    int w1 = __builtin_amdgcn_cvt_pk_fp8_f32(a1.x, a1.y, 0, false);
    w1 = __builtin_amdgcn_cvt_pk_fp8_f32(a1.z, a1.w, w1, true);
    return make_int2(w0, w1);
}

// ---------------------------------------------------------------------------
// Kernel 1 (merged prep+gather):
//  blocks [0,2048):  per-row norms of z_i/z_j, positive logit, z_i -> fp8 A
//    written in MFMA-FRAGMENT-TILED layout A_t[row/128][dblk][row%128][64B]
//    so k_gemm's A-fragment loads are perfectly coalesced 2 KB wave reads.
//  blocks [2048,3072): gather 2K=4096 rows (c_k, c_k+1) of z_j -> fp8 G
//    (row-major), plus per-column-pair metadata kmeta[k] = {1/nj(c),
//    1/nj(c+1), c0}. Block 0 zeroes d_out.
// ---------------------------------------------------------------------------
__global__ __launch_bounds__(256) void k_prep(
    const float* __restrict__ zi, const float* __restrict__ zj,
    const int* __restrict__ perm,
    float* __restrict__ ri_arr, float* __restrict__ pos_arr,
    unsigned char* __restrict__ A,
    float4* __restrict__ kmeta, unsigned char* __restrict__ G,
    float* __restrict__ out)
{
    int w = threadIdx.x >> 6, l = threadIdx.x & 63;
    if (blockIdx.x < 2048) {
        if (blockIdx.x == 0 && threadIdx.x < 3) out[threadIdx.x] = 0.f;
        int row = blockIdx.x * 4 + w;
        const float4* zi4 = (const float4*)(zi + (size_t)row * D_SZ);
        const float4* zj4 = (const float4*)(zj + (size_t)row * D_SZ);
        float4 a0 = zi4[2 * l], a1 = zi4[2 * l + 1];
        float4 b0 = zj4[2 * l], b1 = zj4[2 * l + 1];
        float si = a0.x * a0.x + a0.y * a0.y + a0.z * a0.z + a0.w * a0.w
                 + a1.x * a1.x + a1.y * a1.y + a1.z * a1.z + a1.w * a1.w;
        float sj = b0.x * b0.x + b0.y * b0.y + b0.z * b0.z + b0.w * b0.w
                 + b1.x * b1.x + b1.y * b1.y + b1.z * b1.z + b1.w * b1.w;
        float dd = a0.x * b0.x + a0.y * b0.y + a0.z * b0.z + a0.w * b0.w
                 + a1.x * b1.x + a1.y * b1.y + a1.z * b1.z + a1.w * b1.w;
        for (int m = 1; m < 64; m <<= 1) {
            si += __shfl_xor(si, m);
            sj += __shfl_xor(sj, m);
            dd += __shfl_xor(dd, m);
        }
        if (l == 0) {
            float ni = sqrtf(si), nj = sqrtf(sj);
            ri_arr[row] = INV_T / fmaxf(ni, 1e-6f);   // norms ~22; eps never binds
            pos_arr[row] = dd / fmaxf(ni * nj, EPSV) * INV_T;
        }
        // tiled A write: lane l holds k-bytes [l*8, l*8+8) of this row
        size_t dstA = ((size_t)(row >> 7) * 8 + (l >> 3)) * 8192
                    + (size_t)(row & 127) * 64 + (l & 7) * 8;
        *(int2*)(A + dstA) = pack_fp8x8(a0, a1);
    } else {
        __shared__ float srj[4];
        int g = (blockIdx.x - 2048) * 4 + w;        // 0..4095
        int c0 = perm[g >> 1];
        int c = c0 + (g & 1);                       // actual z_j row
        const float4* src = (const float4*)(zj + (size_t)c * D_SZ);
        float4 a0 = src[2 * l], a1 = src[2 * l + 1];
        float s = a0.x * a0.x + a0.y * a0.y + a0.z * a0.z + a0.w * a0.w
                + a1.x * a1.x + a1.y * a1.y + a1.z * a1.z + a1.w * a1.w;
        for (int m = 1; m < 64; m <<= 1) s += __shfl_xor(s, m);
        if (l == 0) srj[w] = 1.0f / fmaxf(sqrtf(s), 1e-6f);
        __syncthreads();
        if ((w & 1) == 0 && l == 0)
            kmeta[g >> 1] = make_float4(srj[w], srj[w + 1],
                                        __int_as_float(c0), 0.f);
        *(int2*)(G + (size_t)g * D_SZ + l * 8) = pack_fp8x8(a0, a1);
    }
}

// ---------------------------------------------------------------------------
// Kernel 2: MX-fp8 MFMA GEMM, TRANSPOSED OUTPUT, BARRIER-FREE K-LOOP.
// 512 blocks (2/CU, single round). Each block owns 128 g-rows: the whole
// G slab [128][512] fp8 = 64 KB sits RESIDENT in LDS (8 dblk-slabs with the
// R8-proven conflict-free 16B-chunk swizzle), staged once via glds + ONE
// __syncthreads. A streams global->VGPR in MFMA fragment layout (k_prep's
// tiled A makes each frag load a fully-coalesced 2 KB wave read), register
// double-buffered one dblk ahead. The K-loop is then pure
// {A-prefetch, ds_read G, 4x mfma_scale} with compiler-scheduled fine
// vmcnt/lgkmcnt - no barrier drains at all (the m97-structure plateau fix).
// Each block runs 4 anchor panels (128 anchors each) against its g slab,
// with the R10 pair-select epilogue per panel.
// XCD mapping: xcd = bid&7 owns g-slabs xcd*4..+4 (L2-resident source).
// ---------------------------------------------------------------------------
__global__ __launch_bounds__(256, 2) void k_gemm(
    const unsigned char* __restrict__ A,    // tiled [64][8][128][64] fp8
    const unsigned char* __restrict__ G,    // [4096][512] fp8
    const float4* __restrict__ kmeta,       // [2048]  {rj0, rj1, c0f, -}
    const float* __restrict__ ri_arr,       // [8192]  INV_T/ni
    const float* __restrict__ pos_arr,      // [8192]
    float* __restrict__ ws_pe, float* __restrict__ ws_pc)  // [8192][64]
{
    __shared__ unsigned char Gsl[8][128 * 64];   // 64 KB resident g tile
    const int tid = threadIdx.x;
    const int l = tid & 63, w = tid >> 6;
    const int wm = w >> 1, wn = w & 1;      // wm: g-half, wn: anchor-half
    const int ln = l & 31, q = l >> 5;      // 32x32 MFMA lane decomposition

    // XCD-aware mapping: 512 blocks; xcd = bid&7 owns g-slab xcd*4..+4
    const int bid = blockIdx.x;
    const int xcd = bid & 7;
    const int slot = bid >> 3;              // 0..63
    const int gTile = xcd * 4 + (slot & 3); // 0..31 (g panel, fixed per block)
    const int aGroup = slot >> 2;           // 0..15 (group of 4 anchor panels)
    const int gBase = gTile * 128;

    // ---- stage the whole G slab (8 dblk-slabs x 8 KB) into LDS, once ----
    #pragma unroll
    for (int it = 0; it < 16; ++it) {
        int fc = it * 256 + tid;            // 16B chunk 0..4095
        int slab = fc >> 9, within = fc & 511;
        int r = within >> 2, s = within & 3;
        int scc = s ^ ((r ^ (r >> 2)) & 3); // XOR swizzle source 16B chunk
        async_cp16(G + (size_t)(gBase + r) * D_SZ + slab * 64 + scc * 16,
                   &Gsl[slab][within * 16]);
    }

    // G frag LDS byte addresses (within one 8 KB slab)
    int gAddr[2][2];
    #pragma unroll
    for (int t = 0; t < 2; ++t) {
        int gr = wm * 64 + t * 32 + ln;
        int xg = (gr ^ (gr >> 2)) & 3;
        gAddr[t][0] = gr * 64 + ((2 * q) ^ xg) * 16;
        gAddr[t][1] = gr * 64 + ((2 * q + 1) ^ xg) * 16;
    }
    // A frag byte offsets within one tiled panel-dblk slab (8192 B)
    int aOff[2][2];
    #pragma unroll
    for (int t = 0; t < 2; ++t) {
        int ar = wn * 64 + t * 32 + ln;
        aOff[t][0] = ar * 64 + q * 32;
        aOff[t][1] = ar * 64 + q * 32 + 16;
    }

    // this block's A stream: 32 consecutive tiled slabs (4 panels x 8 dblks)
    const unsigned char* aPan = A + (size_t)aGroup * 32 * 8192;

    int4 af[2][2][2];                       // [buf][t][half], reg dbuf
    #pragma unroll
    for (int t = 0; t < 2; ++t)
        #pragma unroll
        for (int h = 0; h < 2; ++h)
            af[0][t][h] = *(const int4*)(aPan + aOff[t][h]);   // slab 0

    __syncthreads();                        // G resident (drains all glds)

    #pragma unroll 1
    for (int panel = 0; panel < 4; ++panel) {
        floatx16 acc[2][2] = {};            // [tm: g-subtile][tn: anchor-sub]
        #pragma unroll
        for (int dblk = 0; dblk < 8; ++dblk) {
            const int idx = panel * 8 + dblk;
            const int cur = dblk & 1, nxt = cur ^ 1;   // idx&1 == dblk&1
            if (dblk < 7 || panel < 3) {
                const unsigned char* aNext = aPan + (size_t)(idx + 1) * 8192;
                #pragma unroll
                for (int t = 0; t < 2; ++t)
                    #pragma unroll
                    for (int h = 0; h < 2; ++h)
                        af[nxt][t][h] = *(const int4*)(aNext + aOff[t][h]);
            }
            intx8 gf[2], av[2];
            #pragma unroll
            for (int t = 0; t < 2; ++t) {
                int4 lo = *(const int4*)&Gsl[dblk][gAddr[t][0]];
                int4 hi = *(const int4*)&Gsl[dblk][gAddr[t][1]];
                gf[t][0] = lo.x; gf[t][1] = lo.y; gf[t][2] = lo.z; gf[t][3] = lo.w;
                gf[t][4] = hi.x; gf[t][5] = hi.y; gf[t][6] = hi.z; gf[t][7] = hi.w;
                int4 alo = af[cur][t][0], ahi = af[cur][t][1];
                av[t][0] = alo.x; av[t][1] = alo.y; av[t][2] = alo.z; av[t][3] = alo.w;
                av[t][4] = ahi.x; av[t][5] = ahi.y; av[t][6] = ahi.z; av[t][7] = ahi.w;
            }
            #pragma unroll
            for (int tm = 0; tm < 2; ++tm)
                #pragma unroll
                for (int tn = 0; tn < 2; ++tn)
                    acc[tm][tn] = __builtin_amdgcn_mfma_scale_f32_32x32x64_f8f6f4(
                        gf[tm], av[tn], acc[tm][tn],
                        0, 0,                   // cbsz/blgp = fp8 e4m3
                        0, 0x7f7f7f7f,          // scale A: all-ones (2^0)
                        0, 0x7f7f7f7f);         // scale B: all-ones (2^0)
        }

        // ---- pair-select epilogue for this panel ----
        // C/D (32x32): col = anchor = ln (+tn*32), row = g = (reg&3) +
        // 8*(reg>>2) + 4*q (+tm*32). Regs 4j..4j+3 = column pairs
        // k0 = gTile*64 + wm*32 + tm*16 + 4j + 2q and k0+1.
        const int aBaseP = (aGroup * 4 + panel) * 128;
        const int cb = gTile * 2 + wm;      // 64-g-chunk index, 0..63
        int anc[2]; float riv[2], pv[2], pe[2] = {0.f, 0.f}, pc[2] = {0.f, 0.f};
        #pragma unroll
        for (int tn = 0; tn < 2; ++tn) {
            anc[tn] = aBaseP + wn * 64 + tn * 32 + ln;
            riv[tn] = ri_arr[anc[tn]];      // INV_T / ni
            pv[tn] = pos_arr[anc[tn]];
        }
        #pragma unroll
        for (int tm = 0; tm < 2; ++tm) {
            #pragma unroll
            for (int j = 0; j < 4; ++j) {
                int k0 = gTile * 64 + wm * 32 + tm * 16 + 4 * j + 2 * q;
                float4 m0 = kmeta[k0];
                float4 m1 = kmeta[k0 + 1];
                #pragma unroll
                for (int p = 0; p < 2; ++p) {
                    float4 md = p ? m1 : m0;
                    int c0 = __float_as_int(md.z);
                    int re = 4 * j + 2 * p; // even-g reg; odd is re+1
                    #pragma unroll
                    for (int tn = 0; tn < 2; ++tn) {
                        bool sel = (c0 >= anc[tn]);         // use column c0+1
                        float v = sel ? acc[tm][tn][re + 1] : acc[tm][tn][re];
                        float rj = sel ? md.y : md.x;
                        float logit = v * riv[tn] * rj;
                        pe[tn] += __expf(logit);
                        pc[tn] += (logit > pv[tn]) ? 1.f : 0.f;
                    }
                }
            }
        }
        #pragma unroll
        for (int tn = 0; tn < 2; ++tn) {
            pe[tn] += __shfl_xor(pe[tn], 32);
            pc[tn] += __shfl_xor(pc[tn], 32);
            if (q == 0) {
                ws_pe[(size_t)anc[tn] * 64 + cb] = pe[tn];
                ws_pc[(size_t)anc[tn] * 64 + cb] = pc[tn];
            }
        }
    }
}

// ---------------------------------------------------------------------------
// Kernel 3: per-row finalize + global reduction into d_out[3].
// Wave-per-row: 128 blocks x 256 threads, 64 rows per block (16 rows/wave).
// ---------------------------------------------------------------------------
__global__ __launch_bounds__(256) void k_final(
    const float* __restrict__ ws_pe, const float* __restrict__ ws_pc,
    const float* __restrict__ pos_arr, float* __restrict__ out)
{
    int w = threadIdx.x >> 6, l = threadIdx.x & 63;
    float lsum = 0.f, a1sum = 0.f, a5sum = 0.f;
    #pragma unroll 4
    for (int j = 0; j < 16; ++j) {
        int row = blockIdx.x * 64 + j * 4 + w;
        float pe = ws_pe[(size_t)row * 64 + l];
        float pc = ws_pc[(size_t)row * 64 + l];
        for (int m = 1; m < 64; m <<= 1) {
            pe += __shfl_xor(pe, m);
            pc += __shfl_xor(pc, m);
        }
        if (l == 0) {
            float pos = pos_arr[row];
            lsum += logf(__expf(pos) + pe) - pos;   // logsumexp - pos (logits bounded)
            a1sum += (pc < 0.5f) ? 1.f : 0.f;       // no neg strictly > pos
            a5sum += (pc < 4.5f) ? 1.f : 0.f;       // at most 4 negs strictly > pos
        }
    }
    __shared__ float red[3][4];
    if (l == 0) { red[0][w] = lsum; red[1][w] = a1sum; red[2][w] = a5sum; }
    __syncthreads();
    if (threadIdx.x == 0) {
        float L = red[0][0] + red[0][1] + red[0][2] + red[0][3];
        float A1 = red[1][0] + red[1][1] + red[1][2] + red[1][3];
        float A5 = red[2][0] + red[2][1] + red[2][2] + red[2][3];
        atomicAdd(&out[0], L / (float)B_SZ);
        atomicAdd(&out[1], A1 * (100.f / (float)B_SZ));
        atomicAdd(&out[2], A5 * (100.f / (float)B_SZ));
    }
}

// ---------------------------------------------------------------------------
extern "C" void kernel_launch(void* const* d_in, const int* in_sizes, int n_in,
                              void* d_out, int out_size, void* d_ws, size_t ws_size,
                              hipStream_t stream)
{
    const float* zi = (const float*)d_in[0];
    const float* zj = (const float*)d_in[1];
    const int* perm = (const int*)d_in[2];
    float* out = (float*)d_out;

    // workspace layout (all 16B aligned)
    char* p = (char*)d_ws;
    unsigned char* A = (unsigned char*)p;    p += (size_t)B_SZ * D_SZ;          // 4 MB (tiled)
    unsigned char* G = (unsigned char*)p;    p += (size_t)2 * K_SZ * D_SZ;      // 2 MB
    float* ri_arr = (float*)p;               p += (size_t)B_SZ * 4;
    float* pos_arr = (float*)p;              p += (size_t)B_SZ * 4;
    float4* kmeta = (float4*)p;              p += (size_t)K_SZ * 16;            // 32 KB
    float* ws_pe = (float*)p;                p += (size_t)B_SZ * 64 * 4;        // 2 MB
    float* ws_pc = (float*)p;                p += (size_t)B_SZ * 64 * 4;        // 2 MB

    k_prep<<<2048 + 1024, 256, 0, stream>>>(zi, zj, perm, ri_arr, pos_arr, A,
                                            kmeta, G, out);
    k_gemm<<<512, 256, 0, stream>>>(A, G, kmeta, ri_arr, pos_arr, ws_pe, ws_pc);
    k_final<<<128, 256, 0, stream>>>(ws_pe, ws_pc, pos_arr, out);
}

// Round 12
// 127.167 us; speedup vs baseline: 1.4456x; 1.4456x over previous
//
#include <hip/hip_runtime.h>
#include <cstdint>

#define B_SZ 8192
#define D_SZ 512
#define K_SZ 2048
#define EPSV 1e-8f
// 1/TEMP
#define INV_T 2.0f

typedef float floatx16 __attribute__((ext_vector_type(16)));
typedef int intx8 __attribute__((ext_vector_type(8)));

// async global->LDS, 16B per lane. LDS dest must be wave-uniform base + lane*16.
__device__ __forceinline__ void async_cp16(const void* g, void* l) {
    typedef __attribute__((address_space(1))) unsigned int gds_t;
    typedef __attribute__((address_space(3))) unsigned int lds_t;
    __builtin_amdgcn_global_load_lds((gds_t*)(unsigned long long)g, (lds_t*)l, 16, 0, 0);
}

// pack 8 fp32 -> 8 fp8 e4m3 (OCP, RNE, saturating) as int2
__device__ __forceinline__ int2 pack_fp8x8(float4 a0, float4 a1) {
    int w0 = __builtin_amdgcn_cvt_pk_fp8_f32(a0.x, a0.y, 0, false);
    w0 = __builtin_amdgcn_cvt_pk_fp8_f32(a0.z, a0.w, w0, true);
    int w1 = __builtin_amdgcn_cvt_pk_fp8_f32(a1.x, a1.y, 0, false);
    w1 = __builtin_amdgcn_cvt_pk_fp8_f32(a1.z, a1.w, w1, true);
    return make_int2(w0, w1);
}

// ---------------------------------------------------------------------------
// Kernel 1 (merged prep+gather):
//  blocks [0,2048):  per-row norms of z_i/z_j, positive logit, z_i -> fp8 A
//    written in MFMA-FRAGMENT-TILED layout A_t[row/128][dblk][row%128][64B]
//    (R11-proven correct) so k_gemm reads A-frags straight from global.
//  blocks [2048,3072): gather 2K=4096 rows (c_k, c_k+1) of z_j -> fp8 G
//    (row-major) + per-column-pair metadata kmeta[k] = {1/nj(c), 1/nj(c+1),
//    c0}. Block 0 zeroes d_out.
// ---------------------------------------------------------------------------
__global__ __launch_bounds__(256) void k_prep(
    const float* __restrict__ zi, const float* __restrict__ zj,
    const int* __restrict__ perm,
    float* __restrict__ ri_arr, float* __restrict__ pos_arr,
    unsigned char* __restrict__ A,
    float4* __restrict__ kmeta, unsigned char* __restrict__ G,
    float* __restrict__ out)
{
    int w = threadIdx.x >> 6, l = threadIdx.x & 63;
    if (blockIdx.x < 2048) {
        if (blockIdx.x == 0 && threadIdx.x < 3) out[threadIdx.x] = 0.f;
        int row = blockIdx.x * 4 + w;
        const float4* zi4 = (const float4*)(zi + (size_t)row * D_SZ);
        const float4* zj4 = (const float4*)(zj + (size_t)row * D_SZ);
        float4 a0 = zi4[2 * l], a1 = zi4[2 * l + 1];
        float4 b0 = zj4[2 * l], b1 = zj4[2 * l + 1];
        float si = a0.x * a0.x + a0.y * a0.y + a0.z * a0.z + a0.w * a0.w
                 + a1.x * a1.x + a1.y * a1.y + a1.z * a1.z + a1.w * a1.w;
        float sj = b0.x * b0.x + b0.y * b0.y + b0.z * b0.z + b0.w * b0.w
                 + b1.x * b1.x + b1.y * b1.y + b1.z * b1.z + b1.w * b1.w;
        float dd = a0.x * b0.x + a0.y * b0.y + a0.z * b0.z + a0.w * b0.w
                 + a1.x * b1.x + a1.y * b1.y + a1.z * b1.z + a1.w * b1.w;
        for (int m = 1; m < 64; m <<= 1) {
            si += __shfl_xor(si, m);
            sj += __shfl_xor(sj, m);
            dd += __shfl_xor(dd, m);
        }
        if (l == 0) {
            float ni = sqrtf(si), nj = sqrtf(sj);
            ri_arr[row] = INV_T / fmaxf(ni, 1e-6f);   // norms ~22; eps never binds
            pos_arr[row] = dd / fmaxf(ni * nj, EPSV) * INV_T;
        }
        // tiled A write: lane l holds k-bytes [l*8, l*8+8) of this row
        size_t dstA = ((size_t)(row >> 7) * 8 + (l >> 3)) * 8192
                    + (size_t)(row & 127) * 64 + (l & 7) * 8;
        *(int2*)(A + dstA) = pack_fp8x8(a0, a1);
    } else {
        __shared__ float srj[4];
        int g = (blockIdx.x - 2048) * 4 + w;        // 0..4095
        int c0 = perm[g >> 1];
        int c = c0 + (g & 1);                       // actual z_j row
        const float4* src = (const float4*)(zj + (size_t)c * D_SZ);
        float4 a0 = src[2 * l], a1 = src[2 * l + 1];
        float s = a0.x * a0.x + a0.y * a0.y + a0.z * a0.z + a0.w * a0.w
                + a1.x * a1.x + a1.y * a1.y + a1.z * a1.z + a1.w * a1.w;
        for (int m = 1; m < 64; m <<= 1) s += __shfl_xor(s, m);
        if (l == 0) srj[w] = 1.0f / fmaxf(sqrtf(s), 1e-6f);
        __syncthreads();
        if ((w & 1) == 0 && l == 0)
            kmeta[g >> 1] = make_float4(srj[w], srj[w + 1],
                                        __int_as_float(c0), 0.f);
        *(int2*)(G + (size_t)g * D_SZ + l * 8) = pack_fp8x8(a0, a1);
    }
}

// ---------------------------------------------------------------------------
// Kernel 2: MX-fp8 MFMA GEMM, TRANSPOSED OUTPUT: S^T = G . A^T.
// R10 skeleton (2048 blocks, 128x128 tile, BK=64, dbuf'd G in LDS, XCD-aware
// lockstep walk, pair-select epilogue) with ONE change: A-operand frags load
// DIRECT FROM GLOBAL (tiled layout, L1/L2-resident under the lockstep walk)
// instead of through LDS. This halves LDS writes, halves ds_reads, and
// halves the barrier's vmcnt drain (only G is staged). LDS total 16 KB.
// ---------------------------------------------------------------------------
__global__ __launch_bounds__(256, 4) void k_gemm(
    const unsigned char* __restrict__ A,    // tiled [64][8][128][64] fp8
    const unsigned char* __restrict__ G,    // [4096][512] fp8
    const float4* __restrict__ kmeta,       // [2048]  {rj0, rj1, c0f, -}
    const float* __restrict__ ri_arr,       // [8192]  INV_T/ni
    const float* __restrict__ pos_arr,      // [8192]
    float* __restrict__ ws_pe, float* __restrict__ ws_pc)  // [8192][64]
{
    __shared__ unsigned char Gsl[2][128 * 64];   // g tile, 8 KB per buffer
    const int tid = threadIdx.x;
    const int l = tid & 63, w = tid >> 6;
    const int wm = w >> 1, wn = w & 1;      // wm: g-half, wn: anchor-half
    const int ln = l & 31, q = l >> 5;      // 32x32 MFMA lane decomposition

    // XCD-aware tile mapping: 2048 blocks; xcd = bid&7 owns g-slab xcd*4..+4
    const int bid = blockIdx.x;
    const int xcd = bid & 7;
    const int slot = bid >> 3;              // 0..255
    const int gTile = xcd * 4 + (slot & 3); // 0..31 (G row panel)
    const int aTile = slot >> 2;            // 0..63 (anchor panel)
    const int gBase = gTile * 128;
    const int aBase = aTile * 128;

    // G staging offsets (bytes); 512 16B-chunks per dblk (2 iters x 256)
    size_t gOff[2];
    int ldsOff[2];
    #pragma unroll
    for (int it = 0; it < 2; ++it) {
        int fc = it * 256 + tid;            // 16B chunk 0..511
        int r = fc >> 2, s = fc & 3;
        int scc = s ^ ((r ^ (r >> 2)) & 3); // XOR swizzle source 16B chunk
        gOff[it] = (size_t)(gBase + r) * D_SZ + scc * 16;
        ldsOff[it] = fc * 16;
    }

    floatx16 acc[2][2] = {};                // [tm: g-subtile][tn: anchor-subtile]

    // G frag LDS byte addresses; A frag byte offsets within a tiled slab
    int gAddr[2][2], aOff[2][2];            // [t][chunk half]
    #pragma unroll
    for (int t = 0; t < 2; ++t) {
        int gr = wm * 64 + t * 32 + ln;     // g row (M-operand)
        int xg = (gr ^ (gr >> 2)) & 3;
        gAddr[t][0] = gr * 64 + ((2 * q) ^ xg) * 16;
        gAddr[t][1] = gr * 64 + ((2 * q + 1) ^ xg) * 16;
        int ar = wn * 64 + t * 32 + ln;     // anchor row (N-operand)
        aOff[t][0] = ar * 64 + q * 32;
        aOff[t][1] = ar * 64 + q * 32 + 16;
    }

    // prologue: stage G k-block 0 into buffer 0
    #pragma unroll
    for (int it = 0; it < 2; ++it)
        async_cp16(G + gOff[it], &Gsl[0][ldsOff[it]]);

    #pragma unroll 1
    for (int dblk = 0; dblk < 8; ++dblk) {
        const int cur = dblk & 1, nxt = cur ^ 1;
        __syncthreads();                    // staged G for `cur` is ready
        if (dblk < 7) {
            #pragma unroll
            for (int it = 0; it < 2; ++it)
                async_cp16(G + gOff[it] + (size_t)(dblk + 1) * 64,
                           &Gsl[nxt][ldsOff[it]]);
        }
        // A frags: direct from global (tiled slab = 8 KB, L1/L2-resident)
        const unsigned char* aSlab = A + (size_t)(aTile * 8 + dblk) * 8192;
        intx8 av[2], gf[2];
        #pragma unroll
        for (int t = 0; t < 2; ++t) {
            int4 alo = *(const int4*)(aSlab + aOff[t][0]);
            int4 ahi = *(const int4*)(aSlab + aOff[t][1]);
            av[t][0] = alo.x; av[t][1] = alo.y; av[t][2] = alo.z; av[t][3] = alo.w;
            av[t][4] = ahi.x; av[t][5] = ahi.y; av[t][6] = ahi.z; av[t][7] = ahi.w;
        }
        #pragma unroll
        for (int t = 0; t < 2; ++t) {
            int4 glo = *(const int4*)&Gsl[cur][gAddr[t][0]];
            int4 ghi = *(const int4*)&Gsl[cur][gAddr[t][1]];
            gf[t][0] = glo.x; gf[t][1] = glo.y; gf[t][2] = glo.z; gf[t][3] = glo.w;
            gf[t][4] = ghi.x; gf[t][5] = ghi.y; gf[t][6] = ghi.z; gf[t][7] = ghi.w;
        }
        #pragma unroll
        for (int tm = 0; tm < 2; ++tm)
            #pragma unroll
            for (int tn = 0; tn < 2; ++tn)
                acc[tm][tn] = __builtin_amdgcn_mfma_scale_f32_32x32x64_f8f6f4(
                    gf[tm], av[tn], acc[tm][tn],
                    0, 0,                       // cbsz/blgp = fp8 e4m3
                    0, 0x7f7f7f7f,              // scale A: all-ones (2^0)
                    0, 0x7f7f7f7f);             // scale B: all-ones (2^0)
    }

    // ---- fused epilogue: pair-select then exp, in-register reduction ----
    // C/D layout (32x32): col = anchor = ln (+tn*32), row = g = (reg&3) +
    // 8*(reg>>2) + 4*q (+tm*32). Regs 4j..4j+3 hold 4 consecutive g, i.e.
    // column pairs k0 = gTile*64 + wm*32 + tm*16 + 4j + 2q and k0+1.
    const int cb = gTile * 2 + wm;          // 64-g-chunk index, 0..63
    int anc[2]; float riv[2], pv[2], pe[2] = {0.f, 0.f}, pc[2] = {0.f, 0.f};
    #pragma unroll
    for (int tn = 0; tn < 2; ++tn) {
        anc[tn] = aBase + wn * 64 + tn * 32 + ln;
        riv[tn] = ri_arr[anc[tn]];          // INV_T / ni
        pv[tn] = pos_arr[anc[tn]];
    }
    #pragma unroll
    for (int tm = 0; tm < 2; ++tm) {
        #pragma unroll
        for (int j = 0; j < 4; ++j) {
            int k0 = gTile * 64 + wm * 32 + tm * 16 + 4 * j + 2 * q;
            float4 m0 = kmeta[k0];
            float4 m1 = kmeta[k0 + 1];
            #pragma unroll
            for (int p = 0; p < 2; ++p) {
                float4 md = p ? m1 : m0;
                int c0 = __float_as_int(md.z);
                int re = 4 * j + 2 * p;     // even-g reg; odd is re+1
                #pragma unroll
                for (int tn = 0; tn < 2; ++tn) {
                    bool sel = (c0 >= anc[tn]);             // use column c0+1
                    float v = sel ? acc[tm][tn][re + 1] : acc[tm][tn][re];
                    float rj = sel ? md.y : md.x;
                    float logit = v * riv[tn] * rj;
                    pe[tn] += __expf(logit);
                    pc[tn] += (logit > pv[tn]) ? 1.f : 0.f;
                }
            }
        }
    }
    #pragma unroll
    for (int tn = 0; tn < 2; ++tn) {
        pe[tn] += __shfl_xor(pe[tn], 32);
        pc[tn] += __shfl_xor(pc[tn], 32);
        if (q == 0) {
            ws_pe[(size_t)anc[tn] * 64 + cb] = pe[tn];
            ws_pc[(size_t)anc[tn] * 64 + cb] = pc[tn];
        }
    }
}

// ---------------------------------------------------------------------------
// Kernel 3: per-row finalize + global reduction into d_out[3].
// Wave-per-row: 128 blocks x 256 threads, 64 rows per block (16 rows/wave).
// ---------------------------------------------------------------------------
__global__ __launch_bounds__(256) void k_final(
    const float* __restrict__ ws_pe, const float* __restrict__ ws_pc,
    const float* __restrict__ pos_arr, float* __restrict__ out)
{
    int w = threadIdx.x >> 6, l = threadIdx.x & 63;
    float lsum = 0.f, a1sum = 0.f, a5sum = 0.f;
    #pragma unroll 4
    for (int j = 0; j < 16; ++j) {
        int row = blockIdx.x * 64 + j * 4 + w;
        float pe = ws_pe[(size_t)row * 64 + l];
        float pc = ws_pc[(size_t)row * 64 + l];
        for (int m = 1; m < 64; m <<= 1) {
            pe += __shfl_xor(pe, m);
            pc += __shfl_xor(pc, m);
        }
        if (l == 0) {
            float pos = pos_arr[row];
            lsum += logf(__expf(pos) + pe) - pos;   // logsumexp - pos (logits bounded)
            a1sum += (pc < 0.5f) ? 1.f : 0.f;       // no neg strictly > pos
            a5sum += (pc < 4.5f) ? 1.f : 0.f;       // at most 4 negs strictly > pos
        }
    }
    __shared__ float red[3][4];
    if (l == 0) { red[0][w] = lsum; red[1][w] = a1sum; red[2][w] = a5sum; }
    __syncthreads();
    if (threadIdx.x == 0) {
        float L = red[0][0] + red[0][1] + red[0][2] + red[0][3];
        float A1 = red[1][0] + red[1][1] + red[1][2] + red[1][3];
        float A5 = red[2][0] + red[2][1] + red[2][2] + red[2][3];
        atomicAdd(&out[0], L / (float)B_SZ);
        atomicAdd(&out[1], A1 * (100.f / (float)B_SZ));
        atomicAdd(&out[2], A5 * (100.f / (float)B_SZ));
    }
}

// ---------------------------------------------------------------------------
extern "C" void kernel_launch(void* const* d_in, const int* in_sizes, int n_in,
                              void* d_out, int out_size, void* d_ws, size_t ws_size,
                              hipStream_t stream)
{
    const float* zi = (const float*)d_in[0];
    const float* zj = (const float*)d_in[1];
    const int* perm = (const int*)d_in[2];
    float* out = (float*)d_out;

    // workspace layout (all 16B aligned)
    char* p = (char*)d_ws;
    unsigned char* A = (unsigned char*)p;    p += (size_t)B_SZ * D_SZ;          // 4 MB (tiled)
    unsigned char* G = (unsigned char*)p;    p += (size_t)2 * K_SZ * D_SZ;      // 2 MB
    float* ri_arr = (float*)p;               p += (size_t)B_SZ * 4;
    float* pos_arr = (float*)p;              p += (size_t)B_SZ * 4;
    float4* kmeta = (float4*)p;              p += (size_t)K_SZ * 16;            // 32 KB
    float* ws_pe = (float*)p;                p += (size_t)B_SZ * 64 * 4;        // 2 MB
    float* ws_pc = (float*)p;                p += (size_t)B_SZ * 64 * 4;        // 2 MB

    k_prep<<<2048 + 1024, 256, 0, stream>>>(zi, zj, perm, ri_arr, pos_arr, A,
                                            kmeta, G, out);
    k_gemm<<<2048, 256, 0, stream>>>(A, G, kmeta, ri_arr, pos_arr, ws_pe, ws_pc);
    k_final<<<128, 256, 0, stream>>>(ws_pe, ws_pc, pos_arr, out);
}

// Round 13
// 111.039 us; speedup vs baseline: 1.6556x; 1.1453x over previous
//
#include <hip/hip_runtime.h>
#include <cstdint>

#define B_SZ 8192
#define D_SZ 512
#define K_SZ 2048
#define EPSV 1e-8f
// 1/TEMP
#define INV_T 2.0f

typedef float floatx16 __attribute__((ext_vector_type(16)));
typedef int intx8 __attribute__((ext_vector_type(8)));

// async global->LDS, 16B per lane. LDS dest must be wave-uniform base + lane*16.
__device__ __forceinline__ void async_cp16(const void* g, void* l) {
    typedef __attribute__((address_space(1))) unsigned int gds_t;
    typedef __attribute__((address_space(3))) unsigned int lds_t;
    __builtin_amdgcn_global_load_lds((gds_t*)(unsigned long long)g, (lds_t*)l, 16, 0, 0);
}

// pack 8 fp32 -> 8 fp8 e4m3 (OCP, RNE, saturating) as int2
__device__ __forceinline__ int2 pack_fp8x8(float4 a0, float4 a1) {
    int w0 = __builtin_amdgcn_cvt_pk_fp8_f32(a0.x, a0.y, 0, false);
    w0 = __builtin_amdgcn_cvt_pk_fp8_f32(a0.z, a0.w, w0, true);
    int w1 = __builtin_amdgcn_cvt_pk_fp8_f32(a1.x, a1.y, 0, false);
    w1 = __builtin_amdgcn_cvt_pk_fp8_f32(a1.z, a1.w, w1, true);
    return make_int2(w0, w1);
}

// ---------------------------------------------------------------------------
// Kernel 1 (merged prep+gather):
//  blocks [0,2048):  per-row norms of z_i/z_j, positive logit, z_i -> fp8 A.
//    Blocks [0,64) also zero the per-row atomic accumulators rowacc[16384]
//    (harness poisons ws with 0xAA); block 0 zeroes d_out.
//  blocks [2048,3072): gather 2K=4096 rows (c_k, c_k+1) of z_j -> fp8 G +
//    per-column-pair metadata kmeta[k] = {1/nj(c), 1/nj(c+1), c0}.
// ---------------------------------------------------------------------------
__global__ __launch_bounds__(256) void k_prep(
    const float* __restrict__ zi, const float* __restrict__ zj,
    const int* __restrict__ perm,
    float* __restrict__ ri_arr, float* __restrict__ pos_arr,
    unsigned char* __restrict__ A,
    float4* __restrict__ kmeta, unsigned char* __restrict__ G,
    float* __restrict__ rowacc, float* __restrict__ out)
{
    int w = threadIdx.x >> 6, l = threadIdx.x & 63;
    if (blockIdx.x < 2048) {
        if (blockIdx.x < 64)
            rowacc[blockIdx.x * 256 + threadIdx.x] = 0.f;   // pe[8192] ++ pc[8192]
        if (blockIdx.x == 0 && threadIdx.x < 3) out[threadIdx.x] = 0.f;
        int row = blockIdx.x * 4 + w;
        const float4* zi4 = (const float4*)(zi + (size_t)row * D_SZ);
        const float4* zj4 = (const float4*)(zj + (size_t)row * D_SZ);
        float4 a0 = zi4[2 * l], a1 = zi4[2 * l + 1];
        float4 b0 = zj4[2 * l], b1 = zj4[2 * l + 1];
        float si = a0.x * a0.x + a0.y * a0.y + a0.z * a0.z + a0.w * a0.w
                 + a1.x * a1.x + a1.y * a1.y + a1.z * a1.z + a1.w * a1.w;
        float sj = b0.x * b0.x + b0.y * b0.y + b0.z * b0.z + b0.w * b0.w
                 + b1.x * b1.x + b1.y * b1.y + b1.z * b1.z + b1.w * b1.w;
        float dd = a0.x * b0.x + a0.y * b0.y + a0.z * b0.z + a0.w * b0.w
                 + a1.x * b1.x + a1.y * b1.y + a1.z * b1.z + a1.w * b1.w;
        for (int m = 1; m < 64; m <<= 1) {
            si += __shfl_xor(si, m);
            sj += __shfl_xor(sj, m);
            dd += __shfl_xor(dd, m);
        }
        if (l == 0) {
            float ni = sqrtf(si), nj = sqrtf(sj);
            ri_arr[row] = INV_T / fmaxf(ni, 1e-6f);   // norms ~22; eps never binds
            pos_arr[row] = dd / fmaxf(ni * nj, EPSV) * INV_T;
        }
        *(int2*)(A + (size_t)row * D_SZ + l * 8) = pack_fp8x8(a0, a1);
    } else {
        __shared__ float srj[4];
        int g = (blockIdx.x - 2048) * 4 + w;        // 0..4095
        int c0 = perm[g >> 1];
        int c = c0 + (g & 1);                       // actual z_j row
        const float4* src = (const float4*)(zj + (size_t)c * D_SZ);
        float4 a0 = src[2 * l], a1 = src[2 * l + 1];
        float s = a0.x * a0.x + a0.y * a0.y + a0.z * a0.z + a0.w * a0.w
                + a1.x * a1.x + a1.y * a1.y + a1.z * a1.z + a1.w * a1.w;
        for (int m = 1; m < 64; m <<= 1) s += __shfl_xor(s, m);
        if (l == 0) srj[w] = 1.0f / fmaxf(sqrtf(s), 1e-6f);
        __syncthreads();
        if ((w & 1) == 0 && l == 0)
            kmeta[g >> 1] = make_float4(srj[w], srj[w + 1],
                                        __int_as_float(c0), 0.f);
        *(int2*)(G + (size_t)g * D_SZ + l * 8) = pack_fp8x8(a0, a1);
    }
}

// ---------------------------------------------------------------------------
// Kernel 2: MX-fp8 MFMA GEMM, TRANSPOSED OUTPUT: S^T = G . A^T (R10 config —
// the best measured: 123.6 us total, 0 bank conflicts, FETCH 17.8 MB).
// v_mfma_scale_f32_32x32x64_f8f6f4, unit scales (= plain e4m3 numerics).
// anchor = col = lane, g = row = reg -> in-register reduction; pair-select
// epilogue (one exp per used logit). 128x128 tile, BK=64, 2x2 waves, dbuf
// LDS 2x(8+8) KB, 16B-chunk swizzle slot = c ^ ((r^(r>>2))&3).
// CHANGE vs R10: epilogue atomicAdds per-anchor pe/pc into rowacc[2][8192]
// instead of writing [8192][64] partials (removes 4 MB of writes; contention
// is 64 adds/address).
// XCD-aware mapping: xcd = bid&7 owns a 512-row G slab (L2-resident).
// ---------------------------------------------------------------------------
__global__ __launch_bounds__(256, 4) void k_gemm(
    const unsigned char* __restrict__ A,    // [8192][512] fp8  (anchors)
    const unsigned char* __restrict__ G,    // [4096][512] fp8  (gathered)
    const float4* __restrict__ kmeta,       // [2048]  {rj0, rj1, c0f, -}
    const float* __restrict__ ri_arr,       // [8192]  INV_T/ni
    const float* __restrict__ pos_arr,      // [8192]
    float* __restrict__ rowacc)             // [2][8192] atomic accumulators
{
    __shared__ unsigned char Asl[2][128 * 64];   // anchor tile, 8 KB per buffer
    __shared__ unsigned char Gsl[2][128 * 64];   // g tile
    const int tid = threadIdx.x;
    const int l = tid & 63, w = tid >> 6;
    const int wm = w >> 1, wn = w & 1;      // wm: g-half, wn: anchor-half
    const int ln = l & 31, q = l >> 5;      // 32x32 MFMA lane decomposition

    // XCD-aware tile mapping: 2048 blocks; xcd = bid&7 owns g-slab xcd*4..+4
    const int bid = blockIdx.x;
    const int xcd = bid & 7;
    const int slot = bid >> 3;              // 0..255
    const int gTile = xcd * 4 + (slot & 3); // 0..31 (G row panel)
    const int aTile = slot >> 2;            // 0..63 (anchor panel)
    const int gBase = gTile * 128;
    const int aBase = aTile * 128;

    // staging offsets (bytes); 512 16B-chunks per array per dblk (2 iters x 256)
    size_t aOff[2], gOff[2];
    int ldsOff[2];
    #pragma unroll
    for (int it = 0; it < 2; ++it) {
        int fc = it * 256 + tid;            // 16B chunk 0..511
        int r = fc >> 2, s = fc & 3;
        int scc = s ^ ((r ^ (r >> 2)) & 3); // XOR swizzle source 16B chunk
        aOff[it] = (size_t)(aBase + r) * D_SZ + scc * 16;
        gOff[it] = (size_t)(gBase + r) * D_SZ + scc * 16;
        ldsOff[it] = fc * 16;
    }

    floatx16 acc[2][2] = {};                // [tm: g-subtile][tn: anchor-subtile]

    // frag read addresses (bytes in an 8 KB buffer): lane needs k-bytes
    // [q*32, q*32+32) of its row = pre-swizzle chunks {2q, 2q+1}
    int aAddr[2][2], gAddr[2][2];           // [t][chunk half]
    #pragma unroll
    for (int t = 0; t < 2; ++t) {
        int ar = wn * 64 + t * 32 + ln;     // anchor row (N-operand)
        int xa = (ar ^ (ar >> 2)) & 3;
        aAddr[t][0] = ar * 64 + ((2 * q) ^ xa) * 16;
        aAddr[t][1] = ar * 64 + ((2 * q + 1) ^ xa) * 16;
        int gr = wm * 64 + t * 32 + ln;     // g row (M-operand)
        int xg = (gr ^ (gr >> 2)) & 3;
        gAddr[t][0] = gr * 64 + ((2 * q) ^ xg) * 16;
        gAddr[t][1] = gr * 64 + ((2 * q + 1) ^ xg) * 16;
    }

    // prologue: stage k-block 0 into buffer 0
    #pragma unroll
    for (int it = 0; it < 2; ++it) {
        async_cp16(A + aOff[it], &Asl[0][ldsOff[it]]);
        async_cp16(G + gOff[it], &Gsl[0][ldsOff[it]]);
    }

    #pragma unroll 1
    for (int dblk = 0; dblk < 8; ++dblk) {
        const int cur = dblk & 1, nxt = cur ^ 1;
        __syncthreads();                    // staged data for `cur` is ready
        if (dblk < 7) {
            #pragma unroll
            for (int it = 0; it < 2; ++it) {
                async_cp16(A + aOff[it] + (size_t)(dblk + 1) * 64, &Asl[nxt][ldsOff[it]]);
                async_cp16(G + gOff[it] + (size_t)(dblk + 1) * 64, &Gsl[nxt][ldsOff[it]]);
            }
        }
        intx8 af[2], gf[2];
        #pragma unroll
        for (int t = 0; t < 2; ++t) {
            int4 lo = *(const int4*)&Asl[cur][aAddr[t][0]];
            int4 hi = *(const int4*)&Asl[cur][aAddr[t][1]];
            af[t][0] = lo.x; af[t][1] = lo.y; af[t][2] = lo.z; af[t][3] = lo.w;
            af[t][4] = hi.x; af[t][5] = hi.y; af[t][6] = hi.z; af[t][7] = hi.w;
            int4 glo = *(const int4*)&Gsl[cur][gAddr[t][0]];
            int4 ghi = *(const int4*)&Gsl[cur][gAddr[t][1]];
            gf[t][0] = glo.x; gf[t][1] = glo.y; gf[t][2] = glo.z; gf[t][3] = glo.w;
            gf[t][4] = ghi.x; gf[t][5] = ghi.y; gf[t][6] = ghi.z; gf[t][7] = ghi.w;
        }
        #pragma unroll
        for (int tm = 0; tm < 2; ++tm)
            #pragma unroll
            for (int tn = 0; tn < 2; ++tn)
                acc[tm][tn] = __builtin_amdgcn_mfma_scale_f32_32x32x64_f8f6f4(
                    gf[tm], af[tn], acc[tm][tn],
                    0, 0,                       // cbsz/blgp = fp8 e4m3
                    0, 0x7f7f7f7f,              // scale A: all-ones (2^0)
                    0, 0x7f7f7f7f);             // scale B: all-ones (2^0)
    }

    // ---- fused epilogue: pair-select then exp, in-register reduction ----
    // C/D layout (32x32): col = anchor = ln (+tn*32), row = g = (reg&3) +
    // 8*(reg>>2) + 4*q (+tm*32). Regs 4j..4j+3 hold 4 consecutive g, i.e.
    // column pairs k0 = gTile*64 + wm*32 + tm*16 + 4j + 2q and k0+1.
    int anc[2]; float riv[2], pv[2], pe[2] = {0.f, 0.f}, pc[2] = {0.f, 0.f};
    #pragma unroll
    for (int tn = 0; tn < 2; ++tn) {
        anc[tn] = aBase + wn * 64 + tn * 32 + ln;
        riv[tn] = ri_arr[anc[tn]];          // INV_T / ni
        pv[tn] = pos_arr[anc[tn]];
    }
    #pragma unroll
    for (int tm = 0; tm < 2; ++tm) {
        #pragma unroll
        for (int j = 0; j < 4; ++j) {
            int k0 = gTile * 64 + wm * 32 + tm * 16 + 4 * j + 2 * q;
            float4 m0 = kmeta[k0];
            float4 m1 = kmeta[k0 + 1];
            #pragma unroll
            for (int p = 0; p < 2; ++p) {
                float4 md = p ? m1 : m0;
                int c0 = __float_as_int(md.z);
                int re = 4 * j + 2 * p;     // even-g reg; odd is re+1
                #pragma unroll
                for (int tn = 0; tn < 2; ++tn) {
                    bool sel = (c0 >= anc[tn]);             // use column c0+1
                    float v = sel ? acc[tm][tn][re + 1] : acc[tm][tn][re];
                    float rj = sel ? md.y : md.x;
                    float logit = v * riv[tn] * rj;
                    pe[tn] += __expf(logit);
                    pc[tn] += (logit > pv[tn]) ? 1.f : 0.f;
                }
            }
        }
    }
    #pragma unroll
    for (int tn = 0; tn < 2; ++tn) {
        pe[tn] += __shfl_xor(pe[tn], 32);
        pc[tn] += __shfl_xor(pc[tn], 32);
        if (q == 0) {
            atomicAdd(&rowacc[anc[tn]], pe[tn]);
            atomicAdd(&rowacc[B_SZ + anc[tn]], pc[tn]);
        }
    }
}

// ---------------------------------------------------------------------------
// Kernel 3: tiny finalize — one thread per row, then block+global reduce.
// 32 blocks x 256 threads; reads only rowacc[2][8192] + pos_arr.
// ---------------------------------------------------------------------------
__global__ __launch_bounds__(256) void k_final(
    const float* __restrict__ rowacc, const float* __restrict__ pos_arr,
    float* __restrict__ out)
{
    int row = blockIdx.x * 256 + threadIdx.x;
    float pe = rowacc[row];
    float pc = rowacc[B_SZ + row];
    float pos = pos_arr[row];
    float loss = logf(__expf(pos) + pe) - pos;   // logsumexp - pos (logits bounded)
    float a1 = (pc < 0.5f) ? 1.f : 0.f;          // no neg strictly > pos
    float a5 = (pc < 4.5f) ? 1.f : 0.f;          // at most 4 negs strictly > pos
    for (int m = 1; m < 64; m <<= 1) {
        loss += __shfl_xor(loss, m);
        a1 += __shfl_xor(a1, m);
        a5 += __shfl_xor(a5, m);
    }
    __shared__ float red[3][4];
    int w = threadIdx.x >> 6, l = threadIdx.x & 63;
    if (l == 0) { red[0][w] = loss; red[1][w] = a1; red[2][w] = a5; }
    __syncthreads();
    if (threadIdx.x == 0) {
        float L = red[0][0] + red[0][1] + red[0][2] + red[0][3];
        float A1 = red[1][0] + red[1][1] + red[1][2] + red[1][3];
        float A5 = red[2][0] + red[2][1] + red[2][2] + red[2][3];
        atomicAdd(&out[0], L / (float)B_SZ);
        atomicAdd(&out[1], A1 * (100.f / (float)B_SZ));
        atomicAdd(&out[2], A5 * (100.f / (float)B_SZ));
    }
}

// ---------------------------------------------------------------------------
extern "C" void kernel_launch(void* const* d_in, const int* in_sizes, int n_in,
                              void* d_out, int out_size, void* d_ws, size_t ws_size,
                              hipStream_t stream)
{
    const float* zi = (const float*)d_in[0];
    const float* zj = (const float*)d_in[1];
    const int* perm = (const int*)d_in[2];
    float* out = (float*)d_out;

    // workspace layout (all 16B aligned)
    char* p = (char*)d_ws;
    unsigned char* A = (unsigned char*)p;    p += (size_t)B_SZ * D_SZ;          // 4 MB
    unsigned char* G = (unsigned char*)p;    p += (size_t)2 * K_SZ * D_SZ;      // 2 MB
    float* ri_arr = (float*)p;               p += (size_t)B_SZ * 4;
    float* pos_arr = (float*)p;              p += (size_t)B_SZ * 4;
    float4* kmeta = (float4*)p;              p += (size_t)K_SZ * 16;            // 32 KB
    float* rowacc = (float*)p;               p += (size_t)2 * B_SZ * 4;         // 64 KB

    k_prep<<<2048 + 1024, 256, 0, stream>>>(zi, zj, perm, ri_arr, pos_arr, A,
                                            kmeta, G, rowacc, out);
    k_gemm<<<2048, 256, 0, stream>>>(A, G, kmeta, ri_arr, pos_arr, rowacc);
    k_final<<<32, 256, 0, stream>>>(rowacc, pos_arr, out);
}